// Round 1
// baseline (103.431 us; speedup 1.0000x reference)
//
#include <hip/hip_runtime.h>
#include <hip/hip_bf16.h>

// Problem constants
#define HEIGHT 480
#define WIDTH  640
#define IN_CH  6
#define CIN    8      // p, 1-p, 6 features
#define COUT   32
#define BATCH  8
#define NPTS   16384
// Padded grid: rows 0..482 (point rows 1..481), cols 0..642 (point cols 1..641)
#define GH 483
#define GW 643

// grid layout: [b][gy][gx][cin], cin contiguous (32B per cell, aligned)
__device__ __forceinline__ size_t cell_off(int b, int gy, int gx) {
    return ((((size_t)b * GH + gy) * GW + gx) << 3);
}

__global__ void scatter_kernel(const float4* __restrict__ xytp,
                               const float*  __restrict__ feats,
                               float* __restrict__ grid) {
    int idx = blockIdx.x * blockDim.x + threadIdx.x;
    if (idx >= BATCH * NPTS) return;
    float4 q = xytp[idx];                 // (t, x, y, p)
    int gy = (int)rintf(q.z * (float)HEIGHT) + 1;   // padded coord
    int gx = (int)rintf(q.y * (float)WIDTH) + 1;
    int b  = idx >> 14;                   // NPTS = 16384
    float* cell = grid + cell_off(b, gy, gx);
    float p = q.w;
    atomicAdd(cell + 0, p);
    atomicAdd(cell + 1, 1.0f - p);
    const float* f = feats + (size_t)idx * IN_CH;
    float f0 = f[0], f1 = f[1], f2 = f[2], f3 = f[3], f4 = f[4], f5 = f[5];
    atomicAdd(cell + 2, f0);
    atomicAdd(cell + 3, f1);
    atomicAdd(cell + 4, f2);
    atomicAdd(cell + 5, f3);
    atomicAdd(cell + 6, f4);
    atomicAdd(cell + 7, f5);
}

__global__ void conv_gather_kernel(const float4* __restrict__ xytp,
                                   const float*  __restrict__ grid,
                                   const float*  __restrict__ W,     // [3][3][8][32]
                                   const float*  __restrict__ bias,  // [32]
                                   float* __restrict__ out) {
    int idx = blockIdx.x * blockDim.x + threadIdx.x;
    if (idx >= BATCH * NPTS) return;
    float4 q = xytp[idx];
    int gy = (int)rintf(q.z * (float)HEIGHT);   // un-padded; window = padded rows gy..gy+2
    int gx = (int)rintf(q.y * (float)WIDTH);
    int b  = idx >> 14;

    float acc[COUT];
#pragma unroll
    for (int c = 0; c < COUT; ++c) acc[c] = bias[c];   // uniform -> s_load

    const float* gbase = grid + cell_off(b, gy, gx);

#pragma unroll
    for (int ky = 0; ky < 3; ++ky) {
#pragma unroll
        for (int kx = 0; kx < 3; ++kx) {
            const float* cell = gbase + ((size_t)(ky * GW + kx) << 3);
            float4 g0 = *(const float4*)(cell);
            float4 g1 = *(const float4*)(cell + 4);
            float g[CIN] = {g0.x, g0.y, g0.z, g0.w, g1.x, g1.y, g1.z, g1.w};
            const float* wp = W + (ky * 3 + kx) * CIN * COUT;
#pragma unroll
            for (int ci = 0; ci < CIN; ++ci) {
#pragma unroll
                for (int c = 0; c < COUT; ++c) {
                    acc[c] = fmaf(g[ci], wp[ci * COUT + c], acc[c]);  // wp uniform -> SGPR operand
                }
            }
        }
    }

    float* o = out + (size_t)idx * COUT;
#pragma unroll
    for (int c = 0; c < COUT; c += 4) {
        *(float4*)(o + c) = make_float4(acc[c], acc[c + 1], acc[c + 2], acc[c + 3]);
    }
}

extern "C" void kernel_launch(void* const* d_in, const int* in_sizes, int n_in,
                              void* d_out, int out_size, void* d_ws, size_t ws_size,
                              hipStream_t stream) {
    const float4* xytp  = (const float4*)d_in[0];   // (8,16384,4)
    const float*  feats = (const float*)d_in[1];    // (8,16384,6)
    const float*  W     = (const float*)d_in[2];    // (3,3,8,32)
    const float*  bias  = (const float*)d_in[3];    // (32,)
    float* out = (float*)d_out;                     // (8,16384,32)

    float* grid = (float*)d_ws;
    const size_t grid_bytes = (size_t)BATCH * GH * GW * CIN * sizeof(float); // ~79.5 MB

    hipMemsetAsync(grid, 0, grid_bytes, stream);

    const int total = BATCH * NPTS;      // 131072
    const int blk = 256;
    const int nblk = (total + blk - 1) / blk;

    scatter_kernel<<<nblk, blk, 0, stream>>>(xytp, feats, grid);
    conv_gather_kernel<<<nblk, blk, 0, stream>>>(xytp, grid, W, bias, out);
}